// Round 2
// baseline (522.529 us; speedup 1.0000x reference)
//
#include <hip/hip_runtime.h>
#include <math.h>

#define VSZ 50257
#define HSZ 1024
#define LSZ 2048
#define SHIFT 60.0f

typedef __attribute__((ext_vector_type(8))) short bf16x8;
typedef __attribute__((ext_vector_type(4))) float f32x4;

__device__ __forceinline__ unsigned short f2bf(float f) {
  unsigned int u = __float_as_uint(f);
  u += 0x7FFFu + ((u >> 16) & 1u);  // RNE
  return (unsigned short)(u >> 16);
}

__device__ __forceinline__ float gru1(float gr, float hr, float gz, float hz,
                                      float gn, float ghn, float h0v) {
  float r = 1.f / (1.f + expf(-(gr + hr)));
  float z = 1.f / (1.f + expf(-(gz + hz)));
  float n = tanhf(gn + r * ghn);
  return (1.f - z) * n + z * h0v;
}

// ============ K1: attention GEMV + zero-init + fp32->bf16 conversion ============
// blocks 0..511: attnw GEMV (4 rows/block). 512..708: zero out[0..V).
// 709: zero score_c. 710: zero acc+psum+out[V+H..V+H+1024). 711..1478: convert enc|Wc to bf16.
__global__ void k_attn(const float* __restrict__ Waw, const float* __restrict__ baw,
                       const int* __restrict__ din, const float* __restrict__ emb,
                       const float* __restrict__ h0, const float* __restrict__ enc,
                       const float* __restrict__ Wc, float* __restrict__ attnw,
                       float* __restrict__ out, float* __restrict__ score_c,
                       float* __restrict__ acc, float* __restrict__ psum,
                       unsigned short* __restrict__ bfbuf) {
  int bid = blockIdx.x, tid = threadIdx.x;
  if (bid < 512) {
    int gw = bid * 4 + (tid >> 6);
    int lane = tid & 63;
    const float4* row = (const float4*)(Waw + (size_t)gw * 2048);
    const float4* e4 = (const float4*)(emb + (size_t)din[0] * HSZ);
    const float4* h4 = (const float4*)h0;
    float s = 0.f;
#pragma unroll
    for (int j = 0; j < 4; ++j) {
      float4 a = row[lane + 64 * j];
      float4 b = e4[lane + 64 * j];
      s += a.x * b.x + a.y * b.y + a.z * b.z + a.w * b.w;
    }
#pragma unroll
    for (int j = 0; j < 4; ++j) {
      float4 a = row[256 + lane + 64 * j];
      float4 b = h4[lane + 64 * j];
      s += a.x * b.x + a.y * b.y + a.z * b.z + a.w * b.w;
    }
#pragma unroll
    for (int o = 32; o > 0; o >>= 1) s += __shfl_down(s, o, 64);
    if (lane == 0) attnw[gw] = s + baw[gw];
  } else if (bid < 709) {
    int v = (bid - 512) * 256 + tid;
    if (v < VSZ) out[v] = 0.f;
  } else if (bid == 709) {
#pragma unroll
    for (int k = 0; k < 8; ++k) score_c[tid + 256 * k] = 0.f;
  } else if (bid == 710) {
#pragma unroll
    for (int k = 0; k < 4; ++k) acc[tid + 256 * k] = 0.f;
#pragma unroll
    for (int k = 0; k < 4; ++k) out[VSZ + HSZ + tid + 256 * k] = 0.f;  // final_weights zero
    if (tid == 0) psum[0] = 0.f;
  } else {
    // conversion: 768 blocks x 256 threads x 4 float4 = 786432 float4s
    int cb = bid - 711;
#pragma unroll
    for (int c = 0; c < 4; ++c) {
      int g = cb * 1024 + c * 256 + tid;
      float4 v;
      if (g < 524288) v = ((const float4*)enc)[g];
      else            v = ((const float4*)Wc)[g - 524288];
      ushort4 o;
      o.x = f2bf(v.x); o.y = f2bf(v.y); o.z = f2bf(v.z); o.w = f2bf(v.w);
      *(ushort4*)(bfbuf + (size_t)g * 4) = o;
    }
  }
}

// ============ K2: softmax(attnw) + attn_applied accumulate (+ Wg prefetch) ============
// blocks 0..255: work (64 l-chunks of 32 x 4 h-chunks of 256). 256..1023: prefetch Wg[0..12.6MB)
__global__ void k_attn_apply(const float* __restrict__ attnw, const float* __restrict__ enc,
                             float* __restrict__ acc, const float* __restrict__ Wg) {
  int bid = blockIdx.x, t = threadIdx.x;
  if (bid < 256) {
    __shared__ float red[256];
    __shared__ float sw[32];
    int hb = bid & 3, lb = bid >> 2;  // lb: 0..63, 32 rows each
    float m = -1e30f;
    for (int i = t; i < LSZ; i += 256) m = fmaxf(m, attnw[i]);
    red[t] = m; __syncthreads();
    for (int s = 128; s > 0; s >>= 1) { if (t < s) red[t] = fmaxf(red[t], red[t + s]); __syncthreads(); }
    float gmax = red[0]; __syncthreads();
    float sum = 0.f;
    for (int i = t; i < LSZ; i += 256) sum += expf(attnw[i] - gmax);
    red[t] = sum; __syncthreads();
    for (int s = 128; s > 0; s >>= 1) { if (t < s) red[t] += red[t + s]; __syncthreads(); }
    float inv = 1.f / red[0];
    if (t < 32) sw[t] = expf(attnw[lb * 32 + t] - gmax) * inv;
    __syncthreads();
    int h = hb * 256 + t;
    float s0 = 0.f, s1 = 0.f, s2 = 0.f, s3 = 0.f;
#pragma unroll
    for (int j = 0; j < 32; j += 4) {
      s0 = fmaf(sw[j + 0], enc[(size_t)(lb * 32 + j + 0) * HSZ + h], s0);
      s1 = fmaf(sw[j + 1], enc[(size_t)(lb * 32 + j + 1) * HSZ + h], s1);
      s2 = fmaf(sw[j + 2], enc[(size_t)(lb * 32 + j + 2) * HSZ + h], s2);
      s3 = fmaf(sw[j + 3], enc[(size_t)(lb * 32 + j + 3) * HSZ + h], s3);
    }
    atomicAdd(&acc[h], (s0 + s1) + (s2 + s3));
  } else {
    int pb = bid - 256;  // 0..767, 16KB each -> 12.58 MB of Wg into L3
    const float4* wp = (const float4*)Wg + (size_t)pb * 1024;
    float s = 0.f;
#pragma unroll
    for (int c = 0; c < 4; ++c) { float4 v = wp[c * 256 + t]; s += v.x + v.y + v.z + v.w; }
    asm volatile("" :: "v"(s));  // keep loads alive, no DCE
  }
}

// ============ K3: rnn_in = relu(W_attn_u @ [emb0|attn_applied] + b) (+ Wg prefetch) ============
__global__ void k_rnn(const float* __restrict__ Wau, const float* __restrict__ bau,
                      const int* __restrict__ din, const float* __restrict__ emb,
                      const float* __restrict__ acc, float* __restrict__ rnn_in,
                      const float* __restrict__ Wg) {
  int bid = blockIdx.x, tid = threadIdx.x;
  if (bid < 256) {
    int gw = bid * 4 + (tid >> 6);
    int lane = tid & 63;
    const float4* row = (const float4*)(Wau + (size_t)gw * 2048);
    const float4* e4 = (const float4*)(emb + (size_t)din[0] * HSZ);
    const float4* a4 = (const float4*)acc;
    float s = 0.f;
#pragma unroll
    for (int j = 0; j < 4; ++j) {
      float4 a = row[lane + 64 * j];
      float4 b = e4[lane + 64 * j];
      s += a.x * b.x + a.y * b.y + a.z * b.z + a.w * b.w;
    }
#pragma unroll
    for (int j = 0; j < 4; ++j) {
      float4 a = row[256 + lane + 64 * j];
      float4 b = a4[lane + 64 * j];
      s += a.x * b.x + a.y * b.y + a.z * b.z + a.w * b.w;
    }
#pragma unroll
    for (int o = 32; o > 0; o >>= 1) s += __shfl_down(s, o, 64);
    if (lane == 0) rnn_in[gw] = fmaxf(s + bau[gw], 0.f);
  } else {
    int pb = bid - 256;  // next 12.58 MB of Wg
    const float4* wp = (const float4*)Wg + 786432 + (size_t)pb * 1024;
    float s = 0.f;
#pragma unroll
    for (int c = 0; c < 4; ++c) { float4 v = wp[c * 256 + tid]; s += v.x + v.y + v.z + v.w; }
    asm volatile("" :: "v"(s));
  }
}

// ============ K4: gi/gh gates (6144 rows) + fused copy-GEMM (512 blocks) ============
// GEMM only needs encB/WcB (K1) and h0 -> safe to run here, off the critical tail.
__global__ __launch_bounds__(256) void k_gates(
    const float* __restrict__ Wih, const float* __restrict__ bih,
    const float* __restrict__ xin, const float* __restrict__ Whh,
    const float* __restrict__ bhh, const float* __restrict__ h0,
    float* __restrict__ y,
    const unsigned short* __restrict__ encB, const unsigned short* __restrict__ WcB,
    const float* __restrict__ bc, float* __restrict__ score) {
  int bid = blockIdx.x, tid = threadIdx.x;
  int wave = tid >> 6, lane = tid & 63;
  if (bid < 1536) {
    int gw = bid * 4 + wave;
    const float* W; const float* x; float bv; int r;
    if (gw < 3 * HSZ) { W = Wih; x = xin; r = gw; bv = bih[r]; }
    else              { W = Whh; x = h0;  r = gw - 3 * HSZ; bv = bhh[r]; }
    const float4* row = (const float4*)(W + (size_t)r * HSZ);
    const float4* xv = (const float4*)x;
    float s = 0.f;
#pragma unroll
    for (int j = 0; j < 4; ++j) {
      float4 a = row[lane + 64 * j];
      float4 b = xv[lane + 64 * j];
      s += a.x * b.x + a.y * b.y + a.z * b.z + a.w * b.w;
    }
#pragma unroll
    for (int o = 32; o > 0; o >>= 1) s += __shfl_down(s, o, 64);
    if (lane == 0) y[gw] = s + bv;
  } else {
    // copy-GEMM: 512 blocks of 64x64 tiles (32 l-tiles x 16 h-tiles), bf16 MFMA
    int g = bid - 1536;
    int l0 = (g >> 4) * 64 + wave * 16;
    int h0r = (g & 15) * 64;
    int col = lane & 15, quad = lane >> 4;
    f32x4 accf[4] = {};
    const unsigned short* arow = encB + ((size_t)(l0 + col) << 10) + quad * 8;
#pragma unroll 4
    for (int k0 = 0; k0 < HSZ; k0 += 32) {
      bf16x8 a = *(const bf16x8*)(arow + k0);
#pragma unroll
      for (int ht = 0; ht < 4; ++ht) {
        bf16x8 b = *(const bf16x8*)(WcB + ((size_t)(h0r + ht * 16 + col) << 10) + k0 + quad * 8);
        accf[ht] = __builtin_amdgcn_mfma_f32_16x16x32_bf16(a, b, accf[ht], 0, 0, 0);
      }
    }
    float rsum[4] = {0.f, 0.f, 0.f, 0.f};
#pragma unroll
    for (int ht = 0; ht < 4; ++ht) {
      int h = h0r + ht * 16 + col;
      float bch = bc[h], hw = h0[h];
#pragma unroll
      for (int r = 0; r < 4; ++r) rsum[r] += tanhf(accf[ht][r] + bch) * hw;
    }
#pragma unroll
    for (int o = 1; o < 16; o <<= 1) {
#pragma unroll
      for (int r = 0; r < 4; ++r) rsum[r] += __shfl_xor(rsum[r], o, 64);
    }
    if (col == 0) {
      int lrow = l0 + quad * 4;
#pragma unroll
      for (int r = 0; r < 4; ++r) atomicAdd(&score[VSZ + lrow + r], rsum[r]);
    }
  }
}

// ============ K5: fused GRU + vocab GEMV + exp-sum ============
// blocks 0..6282: GRU prologue -> LDS x, then 8 vocab rows each; per-block exp-sum -> psum.
// block 0 also writes final_hidden. blocks 6283..6290: exp-sum of score_c -> psum.
__global__ __launch_bounds__(256) void k_vocab(
    const float* __restrict__ gi, const float* __restrict__ h0,
    const float* __restrict__ Wg, const float* __restrict__ bg,
    float* __restrict__ score, float* __restrict__ psum, float* __restrict__ out) {
  __shared__ float xs[1024];
  __shared__ float pr[4];
  int bid = blockIdx.x, tid = threadIdx.x;
  if (bid >= 6283) {
    __shared__ float red[256];
    int l = (bid - 6283) * 256 + tid;
    red[tid] = expf(score[VSZ + l] - SHIFT);
    __syncthreads();
    for (int s = 128; s > 0; s >>= 1) { if (tid < s) red[tid] += red[tid + s]; __syncthreads(); }
    if (tid == 0) atomicAdd(psum, red[0]);
    return;
  }
  // GRU prologue: h_new = (1-z)*n + z*h0, each thread 4 elems
  {
    const float4* G  = (const float4*)gi;
    const float4* Hh = (const float4*)(gi + 3072);
    const float4* H0 = (const float4*)h0;
    float4 gr = G[tid], gz = G[256 + tid], gn = G[512 + tid];
    float4 hr = Hh[tid], hz = Hh[256 + tid], hn = Hh[512 + tid];
    float4 h0v = H0[tid];
    float4 xv;
    xv.x = gru1(gr.x, hr.x, gz.x, hz.x, gn.x, hn.x, h0v.x);
    xv.y = gru1(gr.y, hr.y, gz.y, hz.y, gn.y, hn.y, h0v.y);
    xv.z = gru1(gr.z, hr.z, gz.z, hz.z, gn.z, hn.z, h0v.z);
    xv.w = gru1(gr.w, hr.w, gz.w, hz.w, gn.w, hn.w, h0v.w);
    ((float4*)xs)[tid] = xv;
    if (bid == 0) {  // final_hidden (out+VSZ is only 4B-aligned -> scalar stores)
      int b0 = VSZ + tid * 4;
      out[b0] = xv.x; out[b0 + 1] = xv.y; out[b0 + 2] = xv.z; out[b0 + 3] = xv.w;
    }
  }
  __syncthreads();
  int wave = tid >> 6, lane = tid & 63;
  int r0 = bid * 8 + wave * 2;
  int ra = r0 < VSZ ? r0 : VSZ - 1;
  int rb = r0 + 1 < VSZ ? r0 + 1 : VSZ - 1;
  const float4* xv4 = (const float4*)xs;
  float4 x0 = xv4[lane], x1 = xv4[lane + 64], x2 = xv4[lane + 128], x3 = xv4[lane + 192];
  const float4* p0 = (const float4*)(Wg + (size_t)ra * HSZ);
  const float4* p1 = (const float4*)(Wg + (size_t)rb * HSZ);
  float4 a0 = p0[lane], a1 = p0[lane + 64], a2 = p0[lane + 128], a3 = p0[lane + 192];
  float4 b0 = p1[lane], b1 = p1[lane + 64], b2 = p1[lane + 128], b3 = p1[lane + 192];
  float s0 = a0.x * x0.x + a0.y * x0.y + a0.z * x0.z + a0.w * x0.w
           + a1.x * x1.x + a1.y * x1.y + a1.z * x1.z + a1.w * x1.w
           + a2.x * x2.x + a2.y * x2.y + a2.z * x2.z + a2.w * x2.w
           + a3.x * x3.x + a3.y * x3.y + a3.z * x3.z + a3.w * x3.w;
  float s1 = b0.x * x0.x + b0.y * x0.y + b0.z * x0.z + b0.w * x0.w
           + b1.x * x1.x + b1.y * x1.y + b1.z * x1.z + b1.w * x1.w
           + b2.x * x2.x + b2.y * x2.y + b2.z * x2.z + b2.w * x2.w
           + b3.x * x3.x + b3.y * x3.y + b3.z * x3.z + b3.w * x3.w;
#pragma unroll
  for (int o = 32; o > 0; o >>= 1) {
    s0 += __shfl_down(s0, o, 64);
    s1 += __shfl_down(s1, o, 64);
  }
  float e = 0.f;
  if (lane == 0) {
    if (r0 < VSZ) {
      float v = s0 + bg[r0];
      score[r0] = v;
      e += expf(v - SHIFT);
    }
    if (r0 + 1 < VSZ) {
      float v = s1 + bg[r0 + 1];
      score[r0 + 1] = v;
      e += expf(v - SHIFT);
    }
    pr[wave] = e;
  }
  __syncthreads();
  if (tid == 0) atomicAdd(psum, (pr[0] + pr[1]) + (pr[2] + pr[3]));
}

// ============ K6: final probs ============
__global__ void k_final(const float* __restrict__ score, const float* __restrict__ psum,
                        const int* __restrict__ idx, const int* __restrict__ din,
                        const float* __restrict__ enc, float* __restrict__ out) {
  int bid = blockIdx.x, t = threadIdx.x;
  float inv = 1.f / psum[0];
  if (bid < 197) {
    int v = bid * 256 + t;
    if (v < VSZ) atomicAdd(&out[v], expf(score[v] - SHIFT) * inv);
  } else {
    __shared__ float pm[256];
    __shared__ int flag;
    if (t == 0) flag = 0;
    __syncthreads();
    int l0 = (bid - 197) * 256;
    int l = l0 + t;
    float p = expf(score[VSZ + l] - SHIFT) * inv;
    atomicAdd(&out[idx[l]], p);
    int matched = (idx[l] == din[0]);
    pm[t] = matched ? p : 0.f;
    if (matched) atomicExch(&flag, 1);
    __syncthreads();
    if (flag) {
      for (int h = t; h < HSZ; h += 256) {
        float s = 0.f;
        for (int l2 = 0; l2 < 256; ++l2)
          if (pm[l2] != 0.f) s = fmaf(pm[l2], enc[(size_t)(l0 + l2) * HSZ + h], s);
        if (s != 0.f) atomicAdd(&out[VSZ + HSZ + h], s);
      }
    }
  }
}

extern "C" void kernel_launch(void* const* d_in, const int* in_sizes, int n_in,
                              void* d_out, int out_size, void* d_ws, size_t ws_size,
                              hipStream_t stream) {
  const int*   din = (const int*)d_in[0];
  const float* h0  = (const float*)d_in[1];
  const float* enc = (const float*)d_in[2];
  const int*   idx = (const int*)d_in[3];
  const float* emb = (const float*)d_in[4];
  const float* Waw = (const float*)d_in[5];
  const float* baw = (const float*)d_in[6];
  const float* Wau = (const float*)d_in[7];
  const float* bau = (const float*)d_in[8];
  const float* Wih = (const float*)d_in[9];
  const float* bih = (const float*)d_in[10];
  const float* Whh = (const float*)d_in[11];
  const float* bhh = (const float*)d_in[12];
  const float* Wc  = (const float*)d_in[13];
  const float* bc  = (const float*)d_in[14];
  const float* Wg  = (const float*)d_in[15];
  const float* bg  = (const float*)d_in[16];
  float* out = (float*)d_out;
  float* ws  = (float*)d_ws;

  // ws layout (floats), 16B-aligned:
  float* acc    = ws;             // 1024
  float* rnn_in = ws + 1024;      // 1024
  float* gi     = ws + 2048;      // 3072 (+ gh at 5120)
  float* attnw  = ws + 9216;      // 2048
  float* score  = ws + 11264;     // 52305 = [score_g | score_c]
  float* psum   = ws + 63616;     // 1
  unsigned short* bfbuf = (unsigned short*)(ws + 64000);  // enc bf16 (2097152) then Wc bf16 (1048576)
  unsigned short* encB = bfbuf;
  unsigned short* WcB  = bfbuf + 2097152;

  k_attn<<<1479, 256, 0, stream>>>(Waw, baw, din, emb, h0, enc, Wc, attnw, out,
                                   score + VSZ, acc, psum, bfbuf);
  k_attn_apply<<<1024, 256, 0, stream>>>(attnw, enc, acc, Wg);
  k_rnn<<<1024, 256, 0, stream>>>(Wau, bau, din, emb, acc, rnn_in, Wg);
  k_gates<<<2048, 256, 0, stream>>>(Wih, bih, rnn_in, Whh, bhh, h0, gi,
                                    encB, WcB, bc, score);
  k_vocab<<<6291, 256, 0, stream>>>(gi, h0, Wg, bg, score, psum, out);
  k_final<<<205, 256, 0, stream>>>(score, psum, idx, din, enc, out);
}